// Round 9
// baseline (261.718 us; speedup 1.0000x reference)
//
#include <hip/hip_runtime.h>
#include <stdint.h>

#define K_DIM 4096
#define N_DIM 4096
#define M_DIM 8192   // B*S = 4*2048
#define S_ROWS 2048
#define NKT 32       // K tiles of 128 bytes (2 fragments of 64)

typedef int v4i __attribute__((ext_vector_type(4)));

// Fragment-major layout: for matrix rows r (m or n) and k in [0,4096):
//   frag = (r>>4)*64 + (k>>6); lane = (r&15) + ((k>>4)&3)*16; byte = k&15
//   addr = frag*1024 + lane*16 + byte
// One frag = 1 KiB = one wave's mfma_i32_16x16x64_i8 operand, lane-contiguous.

// ---------------- 1. fused prep: absmax (blocks 0..4095) + wtrans (4096..8191) ----------------
__global__ void prep1_kernel(const float* __restrict__ x, unsigned* __restrict__ amax,
                             const int* __restrict__ wq, char* __restrict__ wt) {
    __shared__ unsigned lds[64 * 17];
    if (blockIdx.x < 4096) {
        int b = blockIdx.x >> 10;
        int bx = blockIdx.x & 1023;
        const float4* xb = (const float4*)(x + (size_t)b * S_ROWS * K_DIM);
        int tid = bx * 256 + threadIdx.x;
        const int stride = 1024 * 256;
        float m = 0.f;
#pragma unroll
        for (int i = 0; i < 8; ++i) {
            float4 v = xb[tid + i * stride];
            m = fmaxf(m, fmaxf(fmaxf(fabsf(v.x), fabsf(v.y)),
                               fmaxf(fabsf(v.z), fabsf(v.w))));
        }
#pragma unroll
        for (int off = 32; off; off >>= 1)
            m = fmaxf(m, __shfl_xor(m, off));
        float* red = (float*)lds;
        if ((threadIdx.x & 63) == 0) red[threadIdx.x >> 6] = m;
        __syncthreads();
        if (threadIdx.x == 0) {
            m = fmaxf(fmaxf(red[0], red[1]), fmaxf(red[2], red[3]));
            atomicMax(&amax[b], __float_as_uint(m));
        }
    } else {
        int wb = blockIdx.x - 4096;
        int n0 = (wb & 63) * 64;
        int k0b = (wb >> 6) * 64;
        int t = threadIdx.x;
        int c = t & 63;
        int g = t >> 6;
#pragma unroll
        for (int rep = 0; rep < 4; ++rep) {
            int kb = g * 16 + rep * 4;
            int v0 = wq[(size_t)(k0b + kb + 0) * N_DIM + n0 + c];
            int v1 = wq[(size_t)(k0b + kb + 1) * N_DIM + n0 + c];
            int v2 = wq[(size_t)(k0b + kb + 2) * N_DIM + n0 + c];
            int v3 = wq[(size_t)(k0b + kb + 3) * N_DIM + n0 + c];
            lds[c * 17 + (kb >> 2)] =
                (v0 & 255) | ((v1 & 255) << 8) | ((v2 & 255) << 16) | ((v3 & 255) << 24);
        }
        __syncthreads();
        int row = t >> 2;            // n within tile
        int ch = t & 3;              // 16B chunk along k
        uint4 o;
        o.x = lds[row * 17 + ch * 4 + 0];
        o.y = lds[row * 17 + ch * 4 + 1];
        o.z = lds[row * 17 + ch * 4 + 2];
        o.w = lds[row * 17 + ch * 4 + 3];
        int n = n0 + row;
        int k0 = k0b + ch * 16;
        size_t dst = ((size_t)(n >> 4) * 64 + (k0 >> 6)) * 1024 +
                     (size_t)((n & 15) + ((k0 >> 4) & 3) * 16) * 16;
        *(uint4*)(wt + dst) = o;
    }
}

// ---------------- 2. quantize x -> int8, fragment-major output ----------------
__global__ void quant_kernel(const float* __restrict__ x,
                             const unsigned* __restrict__ amax,
                             char* __restrict__ xq) {
    size_t gid = (size_t)blockIdx.x * 256 + threadIdx.x;
    size_t base = gid * 16;
    int b = (int)(base >> 23);
    float inv = 128.0f / __uint_as_float(amax[b]);
    const float4* xs = (const float4*)(x + base);
    unsigned parts[4];
#pragma unroll
    for (int i = 0; i < 4; ++i) {
        float4 v = xs[i];
        int q0 = max(-128, min(127, (int)rintf(v.x * inv)));
        int q1 = max(-128, min(127, (int)rintf(v.y * inv)));
        int q2 = max(-128, min(127, (int)rintf(v.z * inv)));
        int q3 = max(-128, min(127, (int)rintf(v.w * inv)));
        parts[i] = (q0 & 255) | ((q1 & 255) << 8) | ((q2 & 255) << 16) | ((q3 & 255) << 24);
    }
    int m = (int)(base >> 12);       // row
    int k0 = (int)(base & 4095);     // 16-aligned
    size_t dst = ((size_t)(m >> 4) * 64 + (k0 >> 6)) * 1024 +
                 (size_t)((m & 15) + ((k0 >> 4) & 3) * 16) * 16;
    *(uint4*)(xq + dst) = make_uint4(parts[0], parts[1], parts[2], parts[3]);
}

// ---------------- 3. int8 MFMA GEMM: zero-LDS flatmm ----------------
// 128x128 tile, 4 waves (2m x 2n), 64x64 per wave. Operands fragment-major:
// every A/B fragment is ONE coalesced global_load_dwordx4 (lane-contiguous
// 1 KiB) straight to VGPRs. No LDS, no barriers, no explicit waitcnt --
// waves free-run; MFMA/VMEM overlap via register ping-pong (tile i computes
// while tile i+1 loads; static buffer names, rule #20). Wave pairs request
// identical A (resp. B) addresses -> L1 dedupe. ~210 VGPR -> 2 blocks/CU.
// XCD map: each XCD owns 4 nt columns (B slice 1 MB -> L2-resident);
// mt streams, shared by all XCDs through L3.
__global__ __launch_bounds__(256, 2) void gemmf_kernel(
    const char* __restrict__ A, const char* __restrict__ Bt,
    const float* __restrict__ bias, const unsigned* __restrict__ amax,
    float* __restrict__ out) {
    const int t = threadIdx.x;
    const int l = t & 63;
    const int w = t >> 6;
    const int wm = w >> 1;       // 0..1
    const int wn = w & 1;        // 0..1
    const int rb = l & 15;
    const int sg = l >> 4;

    int bid = blockIdx.x;
    int xcd = bid & 7;
    int idx = bid >> 3;                  // 0..255
    int nt = (xcd << 2) | (idx & 3);     // 0..31
    int mt = idx >> 2;                   // 0..63
    const size_t m0 = (size_t)mt * 128;
    const size_t n0 = (size_t)nt * 128;

    // fragment base pointers (include lane offset)
    const char* aB = A + (((m0 >> 4) + wm * 4) * 64) * 1024 + l * 16;
    const char* bB = Bt + (((n0 >> 4) + wn * 4) * 64) * 1024 + l * 16;

    v4i acc[4][4];
#pragma unroll
    for (int i = 0; i < 4; ++i)
#pragma unroll
        for (int j = 0; j < 4; ++j) acc[i][j] = (v4i){0, 0, 0, 0};

    v4i aX[4][2], bX[4][2], aY[4][2], bY[4][2];

    // LDF: load tile tt (fragments kf=tt*2, tt*2+1) into buf
#define LDF(bufA, bufB, tt)                                                  \
    {                                                                        \
        int kf = (tt) * 2;                                                   \
        _Pragma("unroll")                                                    \
        for (int mi = 0; mi < 4; ++mi) {                                     \
            bufA[mi][0] = *(const v4i*)(aB + mi * 65536 + (size_t)kf * 1024);\
            bufA[mi][1] = *(const v4i*)(aB + mi * 65536 + (size_t)(kf + 1) * 1024); \
        }                                                                    \
        _Pragma("unroll")                                                    \
        for (int ni = 0; ni < 4; ++ni) {                                     \
            bufB[ni][0] = *(const v4i*)(bB + ni * 65536 + (size_t)kf * 1024);\
            bufB[ni][1] = *(const v4i*)(bB + ni * 65536 + (size_t)(kf + 1) * 1024); \
        }                                                                    \
    }

#define MFMA_T(bufA, bufB)                                                   \
    _Pragma("unroll")                                                        \
    for (int mi = 0; mi < 4; ++mi)                                           \
        _Pragma("unroll")                                                    \
        for (int ni = 0; ni < 4; ++ni)                                       \
            _Pragma("unroll")                                                \
            for (int ks = 0; ks < 2; ++ks)                                   \
                acc[mi][ni] = __builtin_amdgcn_mfma_i32_16x16x64_i8(         \
                    bufA[mi][ks], bufB[ni][ks], acc[mi][ni], 0, 0, 0);

    LDF(aX, bX, 0);
    for (int kt = 0; kt < NKT; kt += 2) {
        LDF(aY, bY, kt + 1);             // kt+1 <= 31, always valid
        __builtin_amdgcn_s_setprio(1);
        MFMA_T(aX, bX);                  // tile kt
        __builtin_amdgcn_s_setprio(0);
        {
            int nxt = (kt + 2 < NKT) ? (kt + 2) : (NKT - 1);
            LDF(aX, bX, nxt);            // redundant reload on last iter
        }
        __builtin_amdgcn_s_setprio(1);
        MFMA_T(aY, bY);                  // tile kt+1
        __builtin_amdgcn_s_setprio(0);
    }

    // ---- epilogue: dequant + bias, row-major store order ----
    float scale = __uint_as_float(amax[m0 >> 11]) * (1.0f / 128.0f) * 0.01f;
    float bv[4];
#pragma unroll
    for (int ni = 0; ni < 4; ++ni) bv[ni] = bias[n0 + wn * 64 + ni * 16 + rb];
#pragma unroll
    for (int mi = 0; mi < 4; ++mi) {
#pragma unroll
        for (int rg = 0; rg < 4; ++rg) {
            size_t row = m0 + wm * 64 + mi * 16 + sg * 4 + rg;
            float* orow = out + row * N_DIM + n0 + wn * 64 + rb;
#pragma unroll
            for (int ni = 0; ni < 4; ++ni)
                orow[ni * 16] = (float)acc[mi][ni][rg] * scale + bv[ni];
        }
    }
#undef LDF
#undef MFMA_T
}

extern "C" void kernel_launch(void* const* d_in, const int* in_sizes, int n_in,
                              void* d_out, int out_size, void* d_ws, size_t ws_size,
                              hipStream_t stream) {
    const float* x = (const float*)d_in[0];
    const int* wq = (const int*)d_in[1];
    const float* bias = (const float*)d_in[2];
    float* out = (float*)d_out;

    unsigned* amax = (unsigned*)d_ws;
    char* xq = (char*)d_ws + 256;
    char* wt = (char*)d_ws + 256 + (size_t)M_DIM * K_DIM;

    hipMemsetAsync(d_ws, 0, 16, stream);

    prep1_kernel<<<dim3(8192), 256, 0, stream>>>(x, amax, wq, wt);
    quant_kernel<<<8192, 256, 0, stream>>>(x, amax, xq);
    gemmf_kernel<<<dim3(2048), 256, 0, stream>>>(xq, wt, bias, amax, out);
}

// Round 10
// 229.862 us; speedup vs baseline: 1.1386x; 1.1386x over previous
//
#include <hip/hip_runtime.h>
#include <stdint.h>

#define K_DIM 4096
#define N_DIM 4096
#define M_DIM 8192   // B*S = 4*2048
#define S_ROWS 2048
#define NT 32        // K tiles of 128 bytes

typedef int v4i __attribute__((ext_vector_type(4)));

__device__ __forceinline__ void gload16(const void* g, void* l) {
    __builtin_amdgcn_global_load_lds(
        (const __attribute__((address_space(1))) unsigned int*)g,
        (__attribute__((address_space(3))) unsigned int*)l, 16, 0, 0);
}

__device__ __forceinline__ void barrier() {
    asm volatile("" ::: "memory");
    __builtin_amdgcn_s_barrier();
    asm volatile("" ::: "memory");
}

// B (weights) fragment-major layout: for n-row r, k in [0,4096):
//   frag = (r>>4)*64 + (k>>6); lane = (r&15) + ((k>>4)&3)*16; byte = k&15
// One frag = 1 KiB = one wave's mfma_i32_16x16x64_i8 B-operand, lane-contiguous.

// ---------------- 1. fused prep: absmax (blocks 0..4095) + wtrans (4096..8191) ----------------
__global__ void prep1_kernel(const float* __restrict__ x, unsigned* __restrict__ amax,
                             const int* __restrict__ wq, char* __restrict__ wt) {
    __shared__ unsigned lds[64 * 17];
    if (blockIdx.x < 4096) {
        int b = blockIdx.x >> 10;
        int bx = blockIdx.x & 1023;
        const float4* xb = (const float4*)(x + (size_t)b * S_ROWS * K_DIM);
        int tid = bx * 256 + threadIdx.x;
        const int stride = 1024 * 256;
        float m = 0.f;
#pragma unroll
        for (int i = 0; i < 8; ++i) {
            float4 v = xb[tid + i * stride];
            m = fmaxf(m, fmaxf(fmaxf(fabsf(v.x), fabsf(v.y)),
                               fmaxf(fabsf(v.z), fabsf(v.w))));
        }
#pragma unroll
        for (int off = 32; off; off >>= 1)
            m = fmaxf(m, __shfl_xor(m, off));
        float* red = (float*)lds;
        if ((threadIdx.x & 63) == 0) red[threadIdx.x >> 6] = m;
        __syncthreads();
        if (threadIdx.x == 0) {
            m = fmaxf(fmaxf(red[0], red[1]), fmaxf(red[2], red[3]));
            atomicMax(&amax[b], __float_as_uint(m));
        }
    } else {
        int wb = blockIdx.x - 4096;
        int n0 = (wb & 63) * 64;
        int k0b = (wb >> 6) * 64;
        int t = threadIdx.x;
        int c = t & 63;
        int g = t >> 6;
#pragma unroll
        for (int rep = 0; rep < 4; ++rep) {
            int kb = g * 16 + rep * 4;
            int v0 = wq[(size_t)(k0b + kb + 0) * N_DIM + n0 + c];
            int v1 = wq[(size_t)(k0b + kb + 1) * N_DIM + n0 + c];
            int v2 = wq[(size_t)(k0b + kb + 2) * N_DIM + n0 + c];
            int v3 = wq[(size_t)(k0b + kb + 3) * N_DIM + n0 + c];
            lds[c * 17 + (kb >> 2)] =
                (v0 & 255) | ((v1 & 255) << 8) | ((v2 & 255) << 16) | ((v3 & 255) << 24);
        }
        __syncthreads();
        int row = t >> 2;            // n within tile
        int ch = t & 3;              // 16B chunk along k
        uint4 o;
        o.x = lds[row * 17 + ch * 4 + 0];
        o.y = lds[row * 17 + ch * 4 + 1];
        o.z = lds[row * 17 + ch * 4 + 2];
        o.w = lds[row * 17 + ch * 4 + 3];
        int n = n0 + row;
        int k0 = k0b + ch * 16;
        size_t dst = ((size_t)(n >> 4) * 64 + (k0 >> 6)) * 1024 +
                     (size_t)((n & 15) + ((k0 >> 4) & 3) * 16) * 16;
        *(uint4*)(wt + dst) = o;
    }
}

// ---------------- 2. quantize x -> int8, row-major [M][K] ----------------
__global__ void quant_kernel(const float* __restrict__ x,
                             const unsigned* __restrict__ amax,
                             char* __restrict__ xq) {
    size_t gid = (size_t)blockIdx.x * 256 + threadIdx.x;
    size_t base = gid * 16;
    int b = (int)(base >> 23);
    float inv = 128.0f / __uint_as_float(amax[b]);
    const float4* xs = (const float4*)(x + base);
    unsigned parts[4];
#pragma unroll
    for (int i = 0; i < 4; ++i) {
        float4 v = xs[i];
        int q0 = max(-128, min(127, (int)rintf(v.x * inv)));
        int q1 = max(-128, min(127, (int)rintf(v.y * inv)));
        int q2 = max(-128, min(127, (int)rintf(v.z * inv)));
        int q3 = max(-128, min(127, (int)rintf(v.w * inv)));
        parts[i] = (q0 & 255) | ((q1 & 255) << 8) | ((q2 & 255) << 16) | ((q3 & 255) << 24);
    }
    *(uint4*)(xq + base) = make_uint4(parts[0], parts[1], parts[2], parts[3]);
}

// ---------------- 3. int8 MFMA GEMM: A via LDS, B direct-to-reg (hybrid) ----------------
// BM=BN=256, BK=128 B. 8 waves (2m x 4n), per-wave 128x64 output.
// A: staged to LDS via global_load_lds (XOR-swizzled source, rule #21),
//    2x32KiB double buffer, read as b128 fragments (4-wave reuse per panel).
// B: fragment-major in global; each fragment = ONE coalesced dwordx4 load
//    straight to VGPRs; register ping-pong (bP/bQ, static names, rule #20),
//    prefetched 1 full tile ahead. B panels per XCD = 2 MB -> L2-resident.
// LDS traffic/tile: 32 KiB write + 128 KiB read (was 64+192) -> below MFMA budget.
// Sync: ONE vmcnt(0)+barrier per tile; prefetch depth exactly 1 tile, so
// vmcnt(0) waits precisely the data this tile consumes (robust to reordering).
__global__ __launch_bounds__(512, 2) void gemm8_kernel(
    const char* __restrict__ A, const char* __restrict__ Bt,
    const float* __restrict__ bias, const unsigned* __restrict__ amax,
    float* __restrict__ out) {
    __shared__ char sm[65536];
    const int t = threadIdx.x;
    const int l = t & 63;
    const int w = t >> 6;
    const int wm = w >> 2;       // 0..1
    const int wn = w & 3;        // 0..3
    const int rb = l & 15;
    const int sg = l >> 4;

    // XCD map: xcd owns nt in {2*xcd, 2*xcd+1}, mt streams 0..31.
    int bid = blockIdx.x;
    int xcd = bid & 7;
    int idx = bid >> 3;                  // 0..63
    int nt = (xcd << 1) | (idx & 1);     // 0..15
    int mt = idx >> 1;                   // 0..31
    const size_t m0 = (size_t)mt * 256;
    const size_t n0 = (size_t)nt * 256;

    // A LDS read bases: slot xor depends only on rb&7 and sg
    const int s0 = (sg ^ (rb & 7)) << 4;
    const int s1 = s0 ^ 64;
    const int baseA = (wm * 128 + rb) * 128;

    // B fragment-major base (lane offset folded in)
    const char* bBase = Bt + (((size_t)(n0 >> 4) + wn * 4) * 64) * 1024 + l * 16;

    v4i acc[8][4];
#pragma unroll
    for (int i = 0; i < 8; ++i)
#pragma unroll
        for (int j = 0; j < 4; ++j) acc[i][j] = (v4i){0, 0, 0, 0};

#define ST_A(tt)                                                             \
    if ((tt) < NT) {                                                         \
        char* lb = sm + (((tt) & 1) << 15);                                  \
        const char* ga = A + m0 * K_DIM + (size_t)(tt) * 128;                \
        _Pragma("unroll")                                                    \
        for (int j = 0; j < 4; ++j) {                                        \
            int p = j * 512 + t;                                             \
            int r = p >> 3, sl = p & 7;                                      \
            int s = sl ^ (r & 7);                                            \
            gload16(ga + (size_t)r * K_DIM + s * 16, lb + p * 16);           \
        }                                                                    \
    }

#define LDB(buf, tt)                                                         \
    {                                                                        \
        int tc = (tt) < NT ? (tt) : (NT - 1);                                \
        _Pragma("unroll")                                                    \
        for (int ni = 0; ni < 4; ++ni) {                                     \
            buf[ni][0] = *(const v4i*)(bBase + ni * 65536 + (size_t)(tc * 2) * 1024);     \
            buf[ni][1] = *(const v4i*)(bBase + ni * 65536 + (size_t)(tc * 2 + 1) * 1024); \
        }                                                                    \
    }

#define COMPUTE(i, bCur)                                                     \
    {                                                                        \
        const char* pb = sm + (((i) & 1) << 15);                             \
        const char* pA0 = pb + baseA + s0;                                   \
        const char* pA1 = pb + baseA + s1;                                   \
        _Pragma("unroll")                                                    \
        for (int mi = 0; mi < 4; ++mi) {                                     \
            aF[mi][0] = *(const v4i*)(pA0 + mi * 2048);                      \
            aF[mi][1] = *(const v4i*)(pA1 + mi * 2048);                      \
        }                                                                    \
        __builtin_amdgcn_s_setprio(1);                                       \
        _Pragma("unroll")                                                    \
        for (int mi = 0; mi < 4; ++mi)                                       \
            _Pragma("unroll")                                                \
            for (int ni = 0; ni < 4; ++ni)                                   \
                _Pragma("unroll")                                            \
                for (int ks = 0; ks < 2; ++ks)                               \
                    acc[mi][ni] = __builtin_amdgcn_mfma_i32_16x16x64_i8(     \
                        aF[mi][ks], bCur[ni][ks], acc[mi][ni], 0, 0, 0);     \
        __builtin_amdgcn_s_setprio(0);                                       \
        _Pragma("unroll")                                                    \
        for (int mi = 0; mi < 4; ++mi) {                                     \
            aF[mi][0] = *(const v4i*)(pA0 + mi * 2048 + 8192);               \
            aF[mi][1] = *(const v4i*)(pA1 + mi * 2048 + 8192);               \
        }                                                                    \
        __builtin_amdgcn_s_setprio(1);                                       \
        _Pragma("unroll")                                                    \
        for (int mi = 0; mi < 4; ++mi)                                       \
            _Pragma("unroll")                                                \
            for (int ni = 0; ni < 4; ++ni)                                   \
                _Pragma("unroll")                                            \
                for (int ks = 0; ks < 2; ++ks)                               \
                    acc[mi + 4][ni] = __builtin_amdgcn_mfma_i32_16x16x64_i8( \
                        aF[mi][ks], bCur[ni][ks], acc[mi + 4][ni], 0, 0, 0); \
        __builtin_amdgcn_s_setprio(0);                                       \
    }

    v4i aF[4][2], bP[4][2], bQ[4][2];

    // prologue: tile 0 in flight
    ST_A(0);
    LDB(bP, 0);

    for (int i = 0; i < NT; i += 2) {
        // tile i: compute with bP, prefetch tile i+1
        asm volatile("s_waitcnt vmcnt(0)" ::: "memory");
        barrier();
        ST_A(i + 1);
        LDB(bQ, i + 1);
        COMPUTE(i, bP);

        // tile i+1: compute with bQ, prefetch tile i+2
        asm volatile("s_waitcnt vmcnt(0)" ::: "memory");
        barrier();
        ST_A(i + 2);
        LDB(bP, i + 2);
        COMPUTE(i + 1, bQ);
    }

    // ---- epilogue: dequant + bias, row-major store order ----
    float scale = __uint_as_float(amax[m0 >> 11]) * (1.0f / 128.0f) * 0.01f;
    float bv[4];
#pragma unroll
    for (int ni = 0; ni < 4; ++ni) bv[ni] = bias[n0 + wn * 64 + ni * 16 + rb];
#pragma unroll
    for (int mi = 0; mi < 8; ++mi) {
#pragma unroll
        for (int rg = 0; rg < 4; ++rg) {
            size_t row = m0 + wm * 128 + mi * 16 + sg * 4 + rg;
            float* orow = out + row * N_DIM + n0 + wn * 64 + rb;
#pragma unroll
            for (int ni = 0; ni < 4; ++ni)
                orow[ni * 16] = (float)acc[mi][ni][rg] * scale + bv[ni];
        }
    }
#undef ST_A
#undef LDB
#undef COMPUTE
}

extern "C" void kernel_launch(void* const* d_in, const int* in_sizes, int n_in,
                              void* d_out, int out_size, void* d_ws, size_t ws_size,
                              hipStream_t stream) {
    const float* x = (const float*)d_in[0];
    const int* wq = (const int*)d_in[1];
    const float* bias = (const float*)d_in[2];
    float* out = (float*)d_out;

    unsigned* amax = (unsigned*)d_ws;
    char* xq = (char*)d_ws + 256;
    char* wt = (char*)d_ws + 256 + (size_t)M_DIM * K_DIM;

    hipMemsetAsync(d_ws, 0, 16, stream);

    prep1_kernel<<<dim3(8192), 256, 0, stream>>>(x, amax, wq, wt);
    quant_kernel<<<8192, 256, 0, stream>>>(x, amax, xq);
    gemm8_kernel<<<dim3(512), 512, 0, stream>>>(xq, wt, bias, amax, out);
}

// Round 11
// 229.529 us; speedup vs baseline: 1.1402x; 1.0014x over previous
//
#include <hip/hip_runtime.h>
#include <stdint.h>

#define K_DIM 4096
#define N_DIM 4096
#define M_DIM 8192   // B*S = 4*2048
#define S_ROWS 2048
#define NKT 64       // K tiles of 64 bytes

typedef int v4i __attribute__((ext_vector_type(4)));

__device__ __forceinline__ void gload16(const void* g, void* l) {
    __builtin_amdgcn_global_load_lds(
        (const __attribute__((address_space(1))) unsigned int*)g,
        (__attribute__((address_space(3))) unsigned int*)l, 16, 0, 0);
}

__device__ __forceinline__ void barrier() {
    asm volatile("" ::: "memory");
    __builtin_amdgcn_s_barrier();
    asm volatile("" ::: "memory");
}

// ---------------- 1. fused prep: absmax (blocks 0..4095) + wtrans (4096..8191) ----------------
__global__ void prep1_kernel(const float* __restrict__ x, unsigned* __restrict__ amax,
                             const int* __restrict__ wq, char* __restrict__ wt) {
    __shared__ unsigned lds[64 * 17];
    if (blockIdx.x < 4096) {
        int b = blockIdx.x >> 10;
        int bx = blockIdx.x & 1023;
        const float4* xb = (const float4*)(x + (size_t)b * S_ROWS * K_DIM);
        int tid = bx * 256 + threadIdx.x;
        const int stride = 1024 * 256;
        float m = 0.f;
#pragma unroll
        for (int i = 0; i < 8; ++i) {
            float4 v = xb[tid + i * stride];
            m = fmaxf(m, fmaxf(fmaxf(fabsf(v.x), fabsf(v.y)),
                               fmaxf(fabsf(v.z), fabsf(v.w))));
        }
#pragma unroll
        for (int off = 32; off; off >>= 1)
            m = fmaxf(m, __shfl_xor(m, off));
        float* red = (float*)lds;
        if ((threadIdx.x & 63) == 0) red[threadIdx.x >> 6] = m;
        __syncthreads();
        if (threadIdx.x == 0) {
            m = fmaxf(fmaxf(red[0], red[1]), fmaxf(red[2], red[3]));
            atomicMax(&amax[b], __float_as_uint(m));
        }
    } else {
        int wb = blockIdx.x - 4096;
        int n0 = (wb & 63) * 64;
        int k0 = (wb >> 6) * 64;
        int t = threadIdx.x;
        int c = t & 63;
        int g = t >> 6;
#pragma unroll
        for (int rep = 0; rep < 4; ++rep) {
            int kb = g * 16 + rep * 4;
            int v0 = wq[(size_t)(k0 + kb + 0) * N_DIM + n0 + c];
            int v1 = wq[(size_t)(k0 + kb + 1) * N_DIM + n0 + c];
            int v2 = wq[(size_t)(k0 + kb + 2) * N_DIM + n0 + c];
            int v3 = wq[(size_t)(k0 + kb + 3) * N_DIM + n0 + c];
            lds[c * 17 + (kb >> 2)] =
                (v0 & 255) | ((v1 & 255) << 8) | ((v2 & 255) << 16) | ((v3 & 255) << 24);
        }
        __syncthreads();
        int row = t >> 2;
        int ch = t & 3;
        uint4 o;
        o.x = lds[row * 17 + ch * 4 + 0];
        o.y = lds[row * 17 + ch * 4 + 1];
        o.z = lds[row * 17 + ch * 4 + 2];
        o.w = lds[row * 17 + ch * 4 + 3];
        *(uint4*)(wt + (size_t)(n0 + row) * K_DIM + k0 + ch * 16) = o;
    }
}

// ---------------- 2. quantize x -> int8, row-major [M][K] ----------------
__global__ void quant_kernel(const float* __restrict__ x,
                             const unsigned* __restrict__ amax,
                             char* __restrict__ xq) {
    size_t gid = (size_t)blockIdx.x * 256 + threadIdx.x;
    size_t base = gid * 16;
    int b = (int)(base >> 23);
    float inv = 128.0f / __uint_as_float(amax[b]);
    const float4* xs = (const float4*)(x + base);
    unsigned parts[4];
#pragma unroll
    for (int i = 0; i < 4; ++i) {
        float4 v = xs[i];
        int q0 = max(-128, min(127, (int)rintf(v.x * inv)));
        int q1 = max(-128, min(127, (int)rintf(v.y * inv)));
        int q2 = max(-128, min(127, (int)rintf(v.z * inv)));
        int q3 = max(-128, min(127, (int)rintf(v.w * inv)));
        parts[i] = (q0 & 255) | ((q1 & 255) << 8) | ((q2 & 255) << 16) | ((q3 & 255) << 24);
    }
    *(uint4*)(xq + base) = make_uint4(parts[0], parts[1], parts[2], parts[3]);
}

// ---------------- 3. int8 MFMA GEMM: 256x256 tile, BK=64, tri-buffer counted-vmcnt ----------------
// R4 geometry (256x256, 8 waves 2m x 4n, R4 XCD swizzle) + R8 schedule:
// 3 LDS buffers x 32 KiB (A[256][64] + B[256][64]); depth-2 prefetch.
// Per tile i: vmcnt(4) -- waits stage(i) (issued 2 tiles earlier, ~4000 cyc
// slack); stage(i+1)'s 4 loads STAY IN FLIGHT across the barrier (T4).
// ONE barrier; then ST(i+2) overwrites buf((i+2)%3)=tile i-1 (reads finished
// before this barrier); 12 ds_read_b128 + 32 MFMA (setprio).
// Swizzle (64B rows): 2 rows per 128B line; virtual slot sv=(r&1)*4+sg,
// physical sv^(line&7); inverse applied to global source (rule #21).
// Read-side physical slot is per-thread constant -> immediate-offset reads.
__global__ __launch_bounds__(512, 2) void gemm8_kernel(
    const char* __restrict__ A, const char* __restrict__ Bt,
    const float* __restrict__ bias, const unsigned* __restrict__ amax,
    float* __restrict__ out) {
    __shared__ char sm[98304];   // 3 x 32768
    const int t = threadIdx.x;
    const int l = t & 63;
    const int w = t >> 6;
    const int wm = w >> 2;       // 0..1
    const int wn = w & 3;        // 0..3
    const int rb = l & 15;
    const int sg = l >> 4;       // 16B k-slot 0..3

    int bid = blockIdx.x;
    int swz = (bid & 7) * 64 + (bid >> 3);   // 512 blocks, 8 XCDs, bijective
    int mt = swz >> 4, nt = swz & 15;
    const size_t m0 = (size_t)mt * 256;
    const size_t n0 = (size_t)nt * 256;

    // per-thread constant physical slot + read bases
    const int s = (((rb & 1) << 2) | sg) ^ ((rb >> 1) & 7);
    const int offA = (wm * 64 + (rb >> 1)) * 128 + (s << 4);
    const int offB = 16384 + (wn * 32 + (rb >> 1)) * 128 + (s << 4);

    v4i acc[8][4];
#pragma unroll
    for (int i = 0; i < 8; ++i)
#pragma unroll
        for (int j = 0; j < 4; ++j) acc[i][j] = (v4i){0, 0, 0, 0};

#define ST_FULL(tt, bsel)                                                    \
    if ((tt) < NKT) {                                                        \
        char* lb = sm + (bsel) * 32768;                                      \
        const char* ga = A + m0 * K_DIM + (size_t)(tt) * 64;                 \
        const char* gb = Bt + n0 * K_DIM + (size_t)(tt) * 64;                \
        _Pragma("unroll")                                                    \
        for (int j = 0; j < 2; ++j) {                                        \
            int p = j * 512 + t;                                             \
            int line = p >> 3, sl = p & 7;                                   \
            int sv = sl ^ (line & 7);                                        \
            int r = line * 2 + (sv >> 2), ks = sv & 3;                       \
            gload16(ga + (size_t)r * K_DIM + ks * 16, lb + p * 16);          \
        }                                                                    \
        _Pragma("unroll")                                                    \
        for (int j = 0; j < 2; ++j) {                                        \
            int p = j * 512 + t;                                             \
            int line = p >> 3, sl = p & 7;                                   \
            int sv = sl ^ (line & 7);                                        \
            int r = line * 2 + (sv >> 2), ks = sv & 3;                       \
            gload16(gb + (size_t)r * K_DIM + ks * 16, lb + 16384 + p * 16);  \
        }                                                                    \
    }

    // prologue: stage tiles 0,1 into bufs 0,1
    ST_FULL(0, 0);
    ST_FULL(1, 1);

    v4i aF[8], bF[4];
    int cur = 0;

    for (int i = 0; i < NKT; ++i) {
        if (i == NKT - 1) { asm volatile("s_waitcnt vmcnt(0)" ::: "memory"); }
        else             { asm volatile("s_waitcnt vmcnt(4)" ::: "memory"); }
        barrier();

        int s2 = cur + 2; if (s2 >= 3) s2 -= 3;
        ST_FULL(i + 2, s2);

        const char* pb = sm + cur * 32768;
        const char* pA = pb + offA;
        const char* pB = pb + offB;
#pragma unroll
        for (int ni = 0; ni < 4; ++ni) bF[ni] = *(const v4i*)(pB + ni * 1024);
#pragma unroll
        for (int mi = 0; mi < 8; ++mi) aF[mi] = *(const v4i*)(pA + mi * 1024);

        __builtin_amdgcn_s_setprio(1);
#pragma unroll
        for (int mi = 0; mi < 8; ++mi)
#pragma unroll
            for (int ni = 0; ni < 4; ++ni)
                acc[mi][ni] = __builtin_amdgcn_mfma_i32_16x16x64_i8(
                    aF[mi], bF[ni], acc[mi][ni], 0, 0, 0);
        __builtin_amdgcn_s_setprio(0);

        cur = (cur == 2) ? 0 : cur + 1;
    }

    // ---- epilogue: dequant + bias, row-major store order ----
    float scale = __uint_as_float(amax[m0 >> 11]) * (1.0f / 128.0f) * 0.01f;
    float bv[4];
#pragma unroll
    for (int ni = 0; ni < 4; ++ni) bv[ni] = bias[n0 + wn * 64 + ni * 16 + rb];
#pragma unroll
    for (int mi = 0; mi < 8; ++mi) {
#pragma unroll
        for (int rg = 0; rg < 4; ++rg) {
            size_t row = m0 + wm * 128 + mi * 16 + sg * 4 + rg;
            float* orow = out + row * N_DIM + n0 + wn * 64 + rb;
#pragma unroll
            for (int ni = 0; ni < 4; ++ni)
                orow[ni * 16] = (float)acc[mi][ni][rg] * scale + bv[ni];
        }
    }
#undef ST_FULL
}

extern "C" void kernel_launch(void* const* d_in, const int* in_sizes, int n_in,
                              void* d_out, int out_size, void* d_ws, size_t ws_size,
                              hipStream_t stream) {
    const float* x = (const float*)d_in[0];
    const int* wq = (const int*)d_in[1];
    const float* bias = (const float*)d_in[2];
    float* out = (float*)d_out;

    unsigned* amax = (unsigned*)d_ws;
    char* xq = (char*)d_ws + 256;
    char* wt = (char*)d_ws + 256 + (size_t)M_DIM * K_DIM;

    hipMemsetAsync(d_ws, 0, 16, stream);

    prep1_kernel<<<dim3(8192), 256, 0, stream>>>(x, amax, wq, wt);
    quant_kernel<<<8192, 256, 0, stream>>>(x, amax, xq);
    gemm8_kernel<<<dim3(512), 512, 0, stream>>>(xq, wt, bias, amax, out);
}